// Round 1
// 108.850 us; speedup vs baseline: 1.0551x; 1.0551x over previous
//
#include <hip/hip_runtime.h>
#include <stdint.h>

typedef unsigned long long u64;

#define NNODE 4096
#define NG    8
#define M     512      // nodes per graph
#define W     8        // 64-bit words per 512-bit mask

// workspace layout (bytes)
#define OFF_MASK 0                         // u64[4096][8]     = 262144 B
#define OFF_DEG  (262144)                  // float[4096]      =  16384 B
#define OFF_F1   (262144 + 16384)          // float[4096]      =  16384 B
#define OFF_FEAT (262144 + 32768)          // float[8][7][512] = 114688 B

// ---------------------------------------------------------------------------
// Kernel 1: pack diagonal-block adjacency rows into 512-bit masks + degrees.
// One wave per row; lane l covers columns [8l, 8l+8) of the block.
// ---------------------------------------------------------------------------
__global__ __launch_bounds__(256) void k_pack(const float* __restrict__ A,
                                              u64* __restrict__ gmask,
                                              float* __restrict__ gdeg) {
    int row  = (blockIdx.x << 2) + (threadIdx.x >> 6);  // 0..4095
    int lane = threadIdx.x & 63;
    int lo   = (row >> 9) << 9;                         // block column base
    const float* rowp = A + (size_t)row * NNODE + lo;
    float4 a = *(const float4*)(rowp + lane * 8);
    float4 b = *(const float4*)(rowp + lane * 8 + 4);
    unsigned int byte =
        (a.x != 0.f ? 1u : 0u) | (a.y != 0.f ? 2u : 0u) |
        (a.z != 0.f ? 4u : 0u) | (a.w != 0.f ? 8u : 0u) |
        (b.x != 0.f ? 16u : 0u) | (b.y != 0.f ? 32u : 0u) |
        (b.z != 0.f ? 64u : 0u) | (b.w != 0.f ? 128u : 0u);
    ((unsigned char*)gmask)[(size_t)row * 64 + lane] = (unsigned char)byte;
    int c = __popc(byte);
#pragma unroll
    for (int off = 32; off; off >>= 1) c += __shfl_down(c, off, 64);
    if (lane == 0) gdeg[row] = (float)c;
}

static __device__ __forceinline__ u64 shfl_xor_u64(u64 v, int mask) {
    return ((u64)(unsigned)__shfl_xor((int)(v >> 32), mask, 64) << 32) |
           (u64)(unsigned)__shfl_xor((int)(v & 0xffffffffu), mask, 64);
}

// ---------------------------------------------------------------------------
// Kernel 2: sparse ego-net features. Block = (graph, 16-node chunk) -> 256
// blocks (full device). 16 threads per node; thread q scans the 32-bit half
// h=q&1 of word w=q>>1. reach[] combined by butterfly reduce-scatter so
// thread q owns fully-reduced word bitrev3(q&7); the 9-bit-plane popcount
// epilogue (f5 = M2@deg on q<8, f2 = A@deg on q>=8) is distributed across
// the word owners. All integer/bitwise -> bit-exact vs previous version.
// ---------------------------------------------------------------------------
__global__ __launch_bounds__(256) void k_feat(const u64* __restrict__ gmask,
                                              const float* __restrict__ gdeg,
                                              float* __restrict__ featg,
                                              float* __restrict__ f1g) {
    int g = blockIdx.x >> 5, chunk = blockIdx.x & 31;
    int t = threadIdx.x;
    __shared__ u64 smT[W * M];      // transposed [w][node], 32 KB
    __shared__ float sdeg[M];
    __shared__ u64 planes[9][W];    // degree bit-planes

    // stage full graph mask (32 KB) with 16B vector loads; transpose into LDS
    const ulonglong2* gm2 = (const ulonglong2*)(gmask + (size_t)g * M * W);
#pragma unroll
    for (int it = 0; it < 8; it++) {
        int idx = t + (it << 8);            // 0..2047
        ulonglong2 v = gm2[idx];
        int u = idx >> 2, w2 = (idx & 3) << 1;
        smT[w2 * M + u]       = v.x;
        smT[(w2 + 1) * M + u] = v.y;
    }
    for (int i = t; i < M; i += 256) sdeg[i] = gdeg[g * M + i];
    __syncthreads();

    int wv = t >> 6, lane = t & 63;
    for (int w = wv; w < W; w += 4) {       // wave wv builds words wv, wv+4
        int d = (int)sdeg[(w << 6) + lane];
#pragma unroll
        for (int k = 0; k < 9; k++) {
            u64 bal = __ballot(((d >> k) & 1) != 0);
            if (lane == 0) planes[k][w] = bal;
        }
    }
    __syncthreads();

    int nl = t >> 4, q = t & 15;            // node-in-chunk, sub-thread id
    int n  = (chunk << 4) + nl;

    u64 m1[W];
#pragma unroll
    for (int ww = 0; ww < W; ww++) m1[ww] = smT[ww * M + n];
    m1[n >> 6] |= 1ull << (n & 63);         // M1 = A | I

    u64 reach[W];
#pragma unroll
    for (int ww = 0; ww < W; ww++) reach[ww] = 0ull;

    // my 32-bit half of word w (re-read from LDS: runtime w would spill m1[])
    int w = q >> 1, h = q & 1;
    u64 myw = smT[w * M + n];
    if (w == (n >> 6)) myw |= 1ull << (n & 63);
    unsigned int bits = h ? (unsigned int)(myw >> 32) : (unsigned int)myw;
    int base = (w << 6) + (h << 5);

    int f4 = 0;
    while (bits) {                           // sparse: u in ego1(n)
        int b = __ffs(bits) - 1;
        bits &= bits - 1;
        int u = base + b;
#pragma unroll
        for (int w2 = 0; w2 < W; w2++) {
            u64 r = smT[w2 * M + u];
            reach[w2] |= r;                  // B>0 mask (A symmetric)
            f4 += __popcll(r & m1[w2]);      // edges ego1 -> ego1
        }
    }

    // butterfly reduce-scatter of reach over the 16 threads of this node:
    // after 4 steps, thread q holds fully-reduced word wq (compile-time regs).
    u64 s4[4];
#pragma unroll
    for (int i = 0; i < 4; i++) {
        u64 keep = (q & 1) ? reach[i + 4] : reach[i];
        u64 send = (q & 1) ? reach[i]     : reach[i + 4];
        s4[i] = keep | shfl_xor_u64(send, 1);
    }
    u64 s2[2];
#pragma unroll
    for (int i = 0; i < 2; i++) {
        u64 keep = (q & 2) ? s4[i + 2] : s4[i];
        u64 send = (q & 2) ? s4[i]     : s4[i + 2];
        s2[i] = keep | shfl_xor_u64(send, 2);
    }
    u64 s1;
    {
        u64 keep = (q & 4) ? s2[1] : s2[0];
        u64 send = (q & 4) ? s2[0] : s2[1];
        s1 = keep | shfl_xor_u64(send, 4);
    }
    u64 rfin = s1 | shfl_xor_u64(s1, 8);
    int wq = ((q & 1) << 2) | (q & 2) | ((q >> 2) & 1);   // owned word

    // distributed bit-plane epilogue for word wq
    u64 aw  = smT[wq * M + n];               // A row word (no self bit)
    u64 m1w = aw;
    if (wq == (n >> 6)) m1w |= 1ull << (n & 63);
    u64 m2m = m1w | rfin;                    // M2 word

    int f5f6 = 0, f2p = 0;
    if (q < 8) {                             // f5 partial (bits 0..19) + f6 (<<20)
        int acc = __popcll(m2m) << 20;
#pragma unroll
        for (int k = 0; k < 9; k++) acc += __popcll(m2m & planes[k][wq]) << k;
        f5f6 = acc;
    } else {                                 // f2 partial: A @ deg
        int acc = 0;
#pragma unroll
        for (int k = 0; k < 9; k++) acc += __popcll(aw & planes[k][wq]) << k;
        f2p = acc;
    }

#pragma unroll
    for (int mk = 1; mk <= 8; mk <<= 1) {
        f4   += __shfl_xor(f4,   mk, 64);
        f5f6 += __shfl_xor(f5f6, mk, 64);
        f2p  += __shfl_xor(f2p,  mk, 64);
    }

    if (q == 0) {
        int f5i = f5f6 & 0xFFFFF;            // < 2^20, exact
        int f6c = f5f6 >> 20;                // <= 512
        float deg = sdeg[n];
        float f4raw = (float)f4;
        float f1 = (deg > 1.f) ? 2.f * (f4raw - deg) / (deg * (deg - 1.f)) : 0.f;
        float* fb = featg + (size_t)g * 7 * M;
        fb[0 * M + n] = deg;
        fb[1 * M + n] = f1;
        fb[2 * M + n] = (deg > 0.f) ? (float)f2p / deg : 0.f;
        fb[4 * M + n] = f4raw * 0.5f;
        fb[5 * M + n] = (float)f5i - 2.f * f4raw;
        fb[6 * M + n] = (float)f6c - deg - 1.f;
        f1g[g * M + n] = f1;
    }
}

// ---------------------------------------------------------------------------
// Kernel 3: f3 = neighbor-mean of f1. Block = (graph, 64-node chunk) -> 64
// blocks, thread per node. Serial ascending scan preserved (bit-exact f3).
// ---------------------------------------------------------------------------
__global__ __launch_bounds__(64) void k_f3(const u64* __restrict__ gmask,
                                           const float* __restrict__ gdeg,
                                           const float* __restrict__ f1g,
                                           float* __restrict__ featg) {
    int g = blockIdx.x >> 3, chunk = blockIdx.x & 7;
    int t = threadIdx.x;                    // 0..63
    __shared__ float f1s[M];
#pragma unroll
    for (int i = 0; i < 8; i++) f1s[t + (i << 6)] = f1g[g * M + t + (i << 6)];
    __syncthreads();

    int n = (chunk << 6) + t;
    const u64* mrow = gmask + ((size_t)g * M + n) * W;  // row-major, 64B/thread
    float sum = 0.f;
#pragma unroll
    for (int w = 0; w < W; w++) {
        u64 bits = mrow[w];                 // A row (no self bit)
        while (bits) {
            int b = __ffsll(bits) - 1;
            bits &= bits - 1;
            sum += f1s[(w << 6) + b];
        }
    }
    float deg = gdeg[g * M + n];
    featg[(size_t)g * 7 * M + 3 * M + n] = (deg > 0.f) ? sum / deg : 0.f;
}

// ---------------------------------------------------------------------------
// Kernel 4: per-(graph,feature) statistics. Block = (g, f, candidate-half).
// Median by rank-count with float4 LDS broadcast; moments in double (half 0).
// ---------------------------------------------------------------------------
__global__ __launch_bounds__(256) void k_stats(const float* __restrict__ featg,
                                               float* __restrict__ out) {
    int blk = blockIdx.x;            // 0..111
    int gf = blk >> 1, half = blk & 1;
    int g = gf / 7, f = gf % 7;
    int t = threadIdx.x;
    __shared__ __align__(16) float sv[M];
    __shared__ double rsum[4], r2[4], r3[4], r4[4];
    __shared__ double smean;

    sv[t]       = featg[(size_t)gf * M + t];
    sv[t + 256] = featg[(size_t)gf * M + t + 256];
    __syncthreads();

    int wv = t >> 6, lane = t & 63;
    if (half == 0) {                 // moments only once per (g,f)
        double s = (double)sv[t] + (double)sv[t + 256];
#pragma unroll
        for (int off = 32; off; off >>= 1) s += __shfl_xor(s, off, 64);
        if (lane == 0) rsum[wv] = s;
        __syncthreads();
        if (t == 0) smean = (rsum[0] + rsum[1] + rsum[2] + rsum[3]) * (1.0 / 512.0);
        __syncthreads();
        double mean = smean;
        double c1 = (double)sv[t] - mean, c2v = (double)sv[t + 256] - mean;
        double a2 = c1 * c1, b2 = c2v * c2v;
        double p2 = a2 + b2, p3 = a2 * c1 + b2 * c2v, p4 = a2 * a2 + b2 * b2;
#pragma unroll
        for (int off = 32; off; off >>= 1) {
            p2 += __shfl_xor(p2, off, 64);
            p3 += __shfl_xor(p3, off, 64);
            p4 += __shfl_xor(p4, off, 64);
        }
        if (lane == 0) { r2[wv] = p2; r3[wv] = p3; r4[wv] = p4; }
        __syncthreads();
        if (t == 0) {
            double m2 = (r2[0] + r2[1] + r2[2] + r2[3]) * (1.0 / 512.0);
            double m3 = (r3[0] + r3[1] + r3[2] + r3[3]) * (1.0 / 512.0);
            double m4 = (r4[0] + r4[1] + r4[2] + r4[3]) * (1.0 / 512.0);
            double sd = sqrt(m2);
            double den3 = m2 * sd;  if (den3 < 1e-4) den3 = 1e-4;
            double den4 = m2 * m2;  if (den4 < 1e-4) den4 = 1e-4;
            out[g * 35 + f]      = (float)smean;
            out[g * 35 + 14 + f] = (float)sd;
            out[g * 35 + 21 + f] = (float)(m3 / den3);
            out[g * 35 + 28 + f] = (float)(m4 / den4);
        }
    }

    // median: lower-middle element = rank 255 (torch.median semantics)
    float cv = sv[half * 256 + t];
    int less = 0, eq = 0;
    for (int j = 0; j < M; j += 4) {
        float4 x = *(const float4*)&sv[j];       // wave-uniform => broadcast
        less += (x.x < cv) + (x.y < cv) + (x.z < cv) + (x.w < cv);
        eq   += (x.x == cv) + (x.y == cv) + (x.z == cv) + (x.w == cv);
    }
    if (less <= 255 && less + eq > 255) out[g * 35 + 7 + f] = cv;
}

extern "C" void kernel_launch(void* const* d_in, const int* in_sizes, int n_in,
                              void* d_out, int out_size, void* d_ws, size_t ws_size,
                              hipStream_t stream) {
    const float* A = (const float*)d_in[0];   // [4096,4096] fp32, block-diagonal 0/1
    float* out = (float*)d_out;               // [8,35] fp32
    char* ws = (char*)d_ws;
    u64*   gmask = (u64*)(ws + OFF_MASK);
    float* gdeg  = (float*)(ws + OFF_DEG);
    float* f1g   = (float*)(ws + OFF_F1);
    float* featg = (float*)(ws + OFF_FEAT);

    k_pack <<<NNODE / 4, 256, 0, stream>>>(A, gmask, gdeg);
    k_feat <<<NG * 32,   256, 0, stream>>>(gmask, gdeg, featg, f1g);
    k_f3   <<<NG * 8,     64, 0, stream>>>(gmask, gdeg, f1g, featg);
    k_stats<<<NG * 7 * 2, 256, 0, stream>>>(featg, out);
}